// Round 5
// baseline (356.107 us; speedup 1.0000x reference)
//
#include <hip/hip_runtime.h>
#include <cstddef>

#define HDIM 2048
#define NE 64
#define TOPK 4
#define BM2 32

// ---------- transpose+scale pre-pass: wt[k][e] = w[e][k] * scale[k] ----------
__global__ __launch_bounds__(256) void transpose_w_kernel(
    const float* __restrict__ w, const float* __restrict__ scale,
    float* __restrict__ wt)
{
    __shared__ float Wl[64][65];
    const int tid = threadIdx.x;
    const int k0 = blockIdx.x * 64;          // grid = HDIM/64 = 32
    #pragma unroll
    for (int q = 0; q < 4; q++) {
        int f = tid + 256 * q;
        int e = f >> 4;
        int k4 = (f & 15) * 4;
        float4 v = *(const float4*)(w + (size_t)e * HDIM + k0 + k4);
        Wl[e][k4 + 0] = v.x; Wl[e][k4 + 1] = v.y;
        Wl[e][k4 + 2] = v.z; Wl[e][k4 + 3] = v.w;
    }
    __syncthreads();
    #pragma unroll
    for (int q = 0; q < 4; q++) {
        int f = tid + 256 * q;
        int k = f >> 4;
        int e4 = (f & 15) * 4;
        float s = scale[k0 + k];
        float4 v;
        v.x = Wl[e4 + 0][k] * s; v.y = Wl[e4 + 1][k] * s;
        v.z = Wl[e4 + 2][k] * s; v.w = Wl[e4 + 3][k] * s;
        *(float4*)(wt + (size_t)(k0 + k) * NE + e4) = v;
    }
}

// ---------- GEMM: 8tok x 8exp register tile, A+B via conflict-free LDS b128 ----------
template<int KS>
__global__ __launch_bounds__(256, 2) void gemm5_kernel(
    const float* __restrict__ x, const float* __restrict__ wt,
    float* __restrict__ sp0,     // partial scores ks=0 (probs region)
    float* __restrict__ spws,    // partial scores ks=1..KS-1
    float* __restrict__ sq,      // [KS][tokens] partial ssq
    int tokens)
{
    constexpr int TOKS = 256;
    constexpr int KR = HDIM / KS;     // k-range per block
    constexpr int NCH = KR / 16;      // 16-k chunks
    __shared__ __align__(16) float As[TOKS][20];   // stride 20: bank-safe for 8-row groups
    __shared__ __align__(16) float Bs[NE][20];     // rows swizzled: e -> 8*(e&7)+(e>>3)

    const int tid = threadIdx.x;
    const int tg = tid >> 3;          // 0..31 token-group; tokens tg+32i
    const int eg = tid & 7;           // experts 8*eg .. 8*eg+7
    const int ks = blockIdx.x & (KS - 1);
    const int tok0 = (blockIdx.x / KS) * TOKS;
    const int k0 = ks * KR;

    // staging maps (coalesced)
    const int stok = tid >> 2, skq = tid & 3;      // A: token p*64+stok, 16B seg skq
    const int bkl = tid >> 4, be4 = tid & 15;      // B: k-row bkl, expert-quad be4

    const float* xa = x + (size_t)(tok0 + stok) * HDIM + k0 + skq * 4;
    const float* wb = wt + (size_t)(k0 + bkl) * NE + be4 * 4;

    float acc[8][8];
    #pragma unroll
    for (int i = 0; i < 8; i++)
        #pragma unroll
        for (int j = 0; j < 8; j++) acc[i][j] = 0.f;
    float ssq[4] = {0.f, 0.f, 0.f, 0.f};
    float4 pa[4];
    float4 pb;

    auto LOAD = [&](int c) {
        #pragma unroll
        for (int p = 0; p < 4; ++p)
            pa[p] = *(const float4*)(xa + (size_t)p * 64 * HDIM + c * 16);
        pb = *(const float4*)(wb + (size_t)c * 16 * NE);
    };
    auto STORE = [&]() {
        #pragma unroll
        for (int p = 0; p < 4; ++p) {
            *(float4*)&As[p * 64 + stok][skq * 4] = pa[p];
            ssq[p] = fmaf(pa[p].x, pa[p].x, ssq[p]);
            ssq[p] = fmaf(pa[p].y, pa[p].y, ssq[p]);
            ssq[p] = fmaf(pa[p].z, pa[p].z, ssq[p]);
            ssq[p] = fmaf(pa[p].w, pa[p].w, ssq[p]);
        }
        float pbf[4] = {pb.x, pb.y, pb.z, pb.w};
        #pragma unroll
        for (int q = 0; q < 4; ++q) {
            int e = 4 * be4 + q;
            Bs[8 * (e & 7) + (e >> 3)][bkl] = pbf[q];   // swizzled row
        }
    };

    LOAD(0);
    STORE();
    __syncthreads();

    for (int c = 0; c < NCH; ++c) {
        if (c + 1 < NCH) LOAD(c + 1);          // in flight under compute (T14)
        #pragma unroll
        for (int kq = 0; kq < 4; ++kq) {
            float4 Bf[8];
            #pragma unroll
            for (int j = 0; j < 8; ++j)
                Bf[j] = *(const float4*)&Bs[8 * j + eg][4 * kq];   // 8-way bcast, no conflict
            #pragma unroll
            for (int i = 0; i < 8; ++i) {
                float4 Ai = *(const float4*)&As[tg + 32 * i][4 * kq];
                #pragma unroll
                for (int j = 0; j < 8; ++j) {
                    acc[i][j] = fmaf(Ai.x, Bf[j].x, acc[i][j]);
                    acc[i][j] = fmaf(Ai.y, Bf[j].y, acc[i][j]);
                    acc[i][j] = fmaf(Ai.z, Bf[j].z, acc[i][j]);
                    acc[i][j] = fmaf(Ai.w, Bf[j].w, acc[i][j]);
                }
            }
        }
        __syncthreads();                        // done reading chunk c
        if (c + 1 < NCH) {
            STORE();                            // compiler inserts vmcnt wait here
            __syncthreads();                    // chunk c+1 visible
        }
    }

    // ssq reduce over the 4 staging lanes of each token (tid^1, tid^2 in-wave)
    #pragma unroll
    for (int p = 0; p < 4; ++p) {
        ssq[p] += __shfl_xor(ssq[p], 1, 64);
        ssq[p] += __shfl_xor(ssq[p], 2, 64);
    }
    if (skq == 0) {
        #pragma unroll
        for (int p = 0; p < 4; ++p)
            sq[(size_t)ks * tokens + tok0 + p * 64 + stok] = ssq[p];
    }

    float* sp = (ks == 0) ? sp0 : (spws + (size_t)(ks - 1) * tokens * NE);
    #pragma unroll
    for (int i = 0; i < 8; ++i) {               // 8 consecutive experts -> 2 float4/token
        size_t off = (size_t)(tok0 + tg + 32 * i) * NE + 8 * eg;
        float4 v0 = {acc[i][0], acc[i][1], acc[i][2], acc[i][3]};
        float4 v1 = {acc[i][4], acc[i][5], acc[i][6], acc[i][7]};
        *(float4*)(sp + off) = v0;
        *(float4*)(sp + off + 4) = v1;
    }
}

// ---------- finisher: tree-sum KS partials, rmsnorm, softmax, top-4 ----------
template<int KS>
__global__ __launch_bounds__(256) void finish5_kernel(
    const float* __restrict__ sp0, const float* __restrict__ spws,
    const float* __restrict__ sq, const float* __restrict__ pes,
    float* __restrict__ probs, float* __restrict__ tkw, float* __restrict__ tki,
    int tokens)
{
    __shared__ float Sl[BM2 * 65];
    __shared__ float Pl[BM2 * 65];
    __shared__ float FN[BM2];
    __shared__ float RS[BM2];

    const int tid = threadIdx.x;
    const int tok0 = blockIdx.x * BM2;          // grid = tokens/32

    if (tid < BM2) {
        float q[KS];
        #pragma unroll
        for (int i = 0; i < KS; i++) q[i] = sq[(size_t)i * tokens + tok0 + tid];
        #pragma unroll
        for (int st = 1; st < KS; st <<= 1)
            #pragma unroll
            for (int i = 0; i < KS; i += 2 * st) q[i] += q[i + st];
        FN[tid] = rsqrtf(q[0] * (1.0f / HDIM) + 1e-6f) * 0.022097086912079612f;
    }
    __syncthreads();

    #pragma unroll
    for (int qq = 0; qq < 2; qq++) {
        int f = tid + 256 * qq;                 // 0..511 float4 of 32x64 tile
        int m = f >> 4;
        int e4 = f & 15;
        float4 t[KS];
        t[0] = ((const float4*)sp0)[(size_t)(tok0 + m) * (NE / 4) + e4];
        #pragma unroll
        for (int i = 1; i < KS; i++)
            t[i] = ((const float4*)(spws + (size_t)(i - 1) * tokens * NE))
                       [(size_t)(tok0 + m) * (NE / 4) + e4];
        #pragma unroll
        for (int st = 1; st < KS; st <<= 1)
            #pragma unroll
            for (int i = 0; i < KS; i += 2 * st) {
                t[i].x += t[i + st].x; t[i].y += t[i + st].y;
                t[i].z += t[i + st].z; t[i].w += t[i + st].w;
            }
        float fn = FN[m];
        int base = m * 65 + e4 * 4;
        Sl[base + 0] = t[0].x * fn; Sl[base + 1] = t[0].y * fn;
        Sl[base + 2] = t[0].z * fn; Sl[base + 3] = t[0].w * fn;
    }
    __syncthreads();

    if (tid < BM2) {
        const int m = tid;
        float mx = -3.0e38f;
        for (int e = 0; e < NE; e++) mx = fmaxf(mx, Sl[m * 65 + e]);
        float sum = 0.f;
        for (int e = 0; e < NE; e++) {
            float p = __expf(Sl[m * 65 + e] - mx);
            Pl[m * 65 + e] = p;
            sum += p;
        }
        RS[m] = 1.0f / sum;
    }
    __syncthreads();

    #pragma unroll
    for (int qq = 0; qq < 2; qq++) {            // coalesced probs write
        int f = tid + 256 * qq;
        int m = f >> 4;
        int e0 = (f & 15) * 4;
        float rs = RS[m];
        float4 pv;
        pv.x = Pl[m * 65 + e0 + 0] * rs;
        pv.y = Pl[m * 65 + e0 + 1] * rs;
        pv.z = Pl[m * 65 + e0 + 2] * rs;
        pv.w = Pl[m * 65 + e0 + 3] * rs;
        *(float4*)&probs[(size_t)(tok0 + m) * NE + e0] = pv;
    }

    if (tid < BM2) {                            // destructive top-4, lowest-index ties
        const int m = tid;
        float wv[TOPK]; int idx[TOPK];
        float wsum = 0.f;
        #pragma unroll
        for (int kk = 0; kk < TOPK; ++kk) {
            float best = -3.0e38f; int bi = 0;
            for (int e = 0; e < NE; e++) {
                float v = Sl[m * 65 + e];
                if (v > best) { best = v; bi = e; }
            }
            Sl[m * 65 + bi] = -3.4e38f;
            float p = Pl[m * 65 + bi];
            wv[kk] = p; idx[kk] = bi; wsum += p;
        }
        float inv = 1.0f / wsum;
        size_t ob = (size_t)(tok0 + m) * TOPK;
        #pragma unroll
        for (int kk = 0; kk < TOPK; kk++) {
            tkw[ob + kk] = wv[kk] * inv * pes[idx[kk]];
            tki[ob + kk] = (float)idx[kk];      // harness reads flat buffer as float32
        }
    }
}

extern "C" void kernel_launch(void* const* d_in, const int* in_sizes, int n_in,
                              void* d_out, int out_size, void* d_ws, size_t ws_size,
                              hipStream_t stream) {
    const float* x     = (const float*)d_in[0];
    const float* w     = (const float*)d_in[1];
    const float* scale = (const float*)d_in[2];
    const float* pes   = (const float*)d_in[3];
    const int tokens = in_sizes[0] / HDIM;      // 16384

    float* probs = (float*)d_out;
    float* tkw   = probs + (size_t)tokens * NE;
    float* tki   = tkw + (size_t)tokens * TOPK;

    const size_t wtN = (size_t)HDIM * NE;
    const size_t spN = (size_t)tokens * NE;
    const size_t need8 = (wtN + 7 * spN + (size_t)8 * tokens) * sizeof(float);
    const int KS = (ws_size >= need8) ? 8 : 4;  // KS = waves/CU; 8 needs ~30 MB ws

    float* wt   = (float*)d_ws;
    float* spws = wt + wtN;
    float* sq   = spws + (size_t)(KS - 1) * spN;
    float* sp0  = probs;                        // overwritten by finisher

    transpose_w_kernel<<<HDIM / 64, 256, 0, stream>>>(w, scale, wt);

    const int grid1 = (tokens / 256) * KS;      // 512 @ KS=8
    if (KS == 8)
        gemm5_kernel<8><<<grid1, 256, 0, stream>>>(x, wt, sp0, spws, sq, tokens);
    else
        gemm5_kernel<4><<<grid1, 256, 0, stream>>>(x, wt, sp0, spws, sq, tokens);

    const int grid2 = tokens / BM2;             // 512
    if (KS == 8)
        finish5_kernel<8><<<grid2, 256, 0, stream>>>(sp0, spws, sq, pes, probs, tkw, tki, tokens);
    else
        finish5_kernel<4><<<grid2, 256, 0, stream>>>(sp0, spws, sq, pes, probs, tkw, tki, tokens);
}

// Round 6
// 120.495 us; speedup vs baseline: 2.9554x; 2.9554x over previous
//
#include <hip/hip_runtime.h>
#include <cstddef>

#define HDIM 2048
#define NE 64
#define TOPK 4
#define BM2 32

// ---------- transpose+scale pre-pass: wt[k][e] = w[e][k] * scale[k] ----------
__global__ __launch_bounds__(256) void transpose_w_kernel(
    const float* __restrict__ w, const float* __restrict__ scale,
    float* __restrict__ wt)
{
    __shared__ float Wl[64][65];
    const int tid = threadIdx.x;
    const int k0 = blockIdx.x * 64;          // grid = HDIM/64 = 32
    #pragma unroll
    for (int q = 0; q < 4; q++) {
        int f = tid + 256 * q;
        int e = f >> 4;
        int k4 = (f & 15) * 4;
        float4 v = *(const float4*)(w + (size_t)e * HDIM + k0 + k4);
        Wl[e][k4 + 0] = v.x; Wl[e][k4 + 1] = v.y;
        Wl[e][k4 + 2] = v.z; Wl[e][k4 + 3] = v.w;
    }
    __syncthreads();
    #pragma unroll
    for (int q = 0; q < 4; q++) {
        int f = tid + 256 * q;
        int k = f >> 4;
        int e4 = (f & 15) * 4;
        float s = scale[k0 + k];
        float4 v;
        v.x = Wl[e4 + 0][k] * s; v.y = Wl[e4 + 1][k] * s;
        v.z = Wl[e4 + 2][k] * s; v.w = Wl[e4 + 3][k] * s;
        *(float4*)(wt + (size_t)(k0 + k) * NE + e4) = v;
    }
}

// ---------- GEMM: 8tok x 8exp register tile, A+B via conflict-free LDS b128 ----------
// NO min-waves launch bound: round-5's (256,2) forced 128 VGPR -> accumulator
// spill -> 1 GB scratch traffic. Live set here ~125 VGPR by construction.
template<int KS>
__global__ __launch_bounds__(256) void gemm6_kernel(
    const float* __restrict__ x, const float* __restrict__ wt,
    float* __restrict__ sp0,     // partial scores ks=0 (probs region)
    float* __restrict__ spws,    // partial scores ks=1..KS-1
    float* __restrict__ sq,      // [KS][tokens] partial ssq
    int tokens)
{
    constexpr int TOKS = 256;
    constexpr int KR = HDIM / KS;     // k-range per block
    constexpr int NCH = KR / 16;      // 16-k chunks
    __shared__ __align__(16) float As[TOKS][20];   // stride 20: bank-safe 8-row groups
    __shared__ __align__(16) float Bs[NE][20];     // rows swizzled: e -> 8*(e&7)+(e>>3)

    const int tid = threadIdx.x;
    const int tg = tid >> 3;          // 0..31 token-group; tokens tg+32i
    const int eg = tid & 7;           // experts 8*eg .. 8*eg+7 (via swizzle)
    const int ks = blockIdx.x & (KS - 1);
    const int tok0 = (blockIdx.x / KS) * TOKS;
    const int k0 = ks * KR;

    // staging maps (coalesced)
    const int stok = tid >> 2, skq = tid & 3;      // A: token p*64+stok, 16B seg skq
    const int bkl = tid >> 4, be4 = tid & 15;      // B: k-row bkl, expert-quad be4

    const float* xa = x + (size_t)(tok0 + stok) * HDIM + k0 + skq * 4;
    const float* wb = wt + (size_t)(k0 + bkl) * NE + be4 * 4;

    float acc[8][8];
    #pragma unroll
    for (int i = 0; i < 8; i++)
        #pragma unroll
        for (int j = 0; j < 8; j++) acc[i][j] = 0.f;
    float ssq[4] = {0.f, 0.f, 0.f, 0.f};
    float4 pa[4];
    float4 pb;

    auto LOAD = [&](int c) {
        #pragma unroll
        for (int p = 0; p < 4; ++p)
            pa[p] = *(const float4*)(xa + (size_t)p * 64 * HDIM + c * 16);
        pb = *(const float4*)(wb + (size_t)c * 16 * NE);
    };
    auto STORE = [&]() {
        #pragma unroll
        for (int p = 0; p < 4; ++p) {
            *(float4*)&As[p * 64 + stok][skq * 4] = pa[p];
            ssq[p] = fmaf(pa[p].x, pa[p].x, ssq[p]);
            ssq[p] = fmaf(pa[p].y, pa[p].y, ssq[p]);
            ssq[p] = fmaf(pa[p].z, pa[p].z, ssq[p]);
            ssq[p] = fmaf(pa[p].w, pa[p].w, ssq[p]);
        }
        float pbf[4] = {pb.x, pb.y, pb.z, pb.w};
        #pragma unroll
        for (int q = 0; q < 4; ++q) {
            int e = 4 * be4 + q;
            Bs[8 * (e & 7) + (e >> 3)][bkl] = pbf[q];   // swizzled row
        }
    };

    LOAD(0);
    STORE();
    __syncthreads();

    for (int c = 0; c < NCH; ++c) {
        if (c + 1 < NCH) LOAD(c + 1);          // in flight under compute (T14)
        #pragma unroll
        for (int kq = 0; kq < 4; ++kq) {
            // preload the 8 A fragments once (32 regs), then stream B one row
            // at a time (4 regs live) -> no spill
            float4 Ai[8];
            #pragma unroll
            for (int i = 0; i < 8; ++i)
                Ai[i] = *(const float4*)&As[tg + 32 * i][4 * kq];
            #pragma unroll
            for (int j = 0; j < 8; ++j) {
                float4 Bf = *(const float4*)&Bs[8 * j + eg][4 * kq];
                #pragma unroll
                for (int i = 0; i < 8; ++i) {
                    acc[i][j] = fmaf(Ai[i].x, Bf.x, acc[i][j]);
                    acc[i][j] = fmaf(Ai[i].y, Bf.y, acc[i][j]);
                    acc[i][j] = fmaf(Ai[i].z, Bf.z, acc[i][j]);
                    acc[i][j] = fmaf(Ai[i].w, Bf.w, acc[i][j]);
                }
            }
        }
        __syncthreads();                        // done reading chunk c
        if (c + 1 < NCH) {
            STORE();
            __syncthreads();                    // chunk c+1 visible
        }
    }

    // ssq reduce over the 4 staging lanes of each token (adjacent lanes)
    #pragma unroll
    for (int p = 0; p < 4; ++p) {
        ssq[p] += __shfl_xor(ssq[p], 1, 64);
        ssq[p] += __shfl_xor(ssq[p], 2, 64);
    }
    if (skq == 0) {
        #pragma unroll
        for (int p = 0; p < 4; ++p)
            sq[(size_t)ks * tokens + tok0 + p * 64 + stok] = ssq[p];
    }

    float* sp = (ks == 0) ? sp0 : (spws + (size_t)(ks - 1) * tokens * NE);
    #pragma unroll
    for (int i = 0; i < 8; ++i) {               // 8 consecutive experts -> 2 float4/token
        size_t off = (size_t)(tok0 + tg + 32 * i) * NE + 8 * eg;
        float4 v0 = {acc[i][0], acc[i][1], acc[i][2], acc[i][3]};
        float4 v1 = {acc[i][4], acc[i][5], acc[i][6], acc[i][7]};
        *(float4*)(sp + off) = v0;
        *(float4*)(sp + off + 4) = v1;
    }
}

// ---------- finisher: tree-sum KS partials, rmsnorm, softmax, top-4 ----------
template<int KS>
__global__ __launch_bounds__(256) void finish6_kernel(
    const float* __restrict__ sp0, const float* __restrict__ spws,
    const float* __restrict__ sq, const float* __restrict__ pes,
    float* __restrict__ probs, float* __restrict__ tkw, float* __restrict__ tki,
    int tokens)
{
    __shared__ float Sl[BM2 * 65];
    __shared__ float Pl[BM2 * 65];
    __shared__ float FN[BM2];
    __shared__ float RS[BM2];

    const int tid = threadIdx.x;
    const int tok0 = blockIdx.x * BM2;          // grid = tokens/32

    if (tid < BM2) {
        float q[KS];
        #pragma unroll
        for (int i = 0; i < KS; i++) q[i] = sq[(size_t)i * tokens + tok0 + tid];
        #pragma unroll
        for (int st = 1; st < KS; st <<= 1)
            #pragma unroll
            for (int i = 0; i < KS; i += 2 * st) q[i] += q[i + st];
        FN[tid] = rsqrtf(q[0] * (1.0f / HDIM) + 1e-6f) * 0.022097086912079612f;
    }
    __syncthreads();

    #pragma unroll
    for (int qq = 0; qq < 2; qq++) {
        int f = tid + 256 * qq;                 // 0..511 float4 of 32x64 tile
        int m = f >> 4;
        int e4 = f & 15;
        float4 t[KS];
        t[0] = ((const float4*)sp0)[(size_t)(tok0 + m) * (NE / 4) + e4];
        #pragma unroll
        for (int i = 1; i < KS; i++)
            t[i] = ((const float4*)(spws + (size_t)(i - 1) * tokens * NE))
                       [(size_t)(tok0 + m) * (NE / 4) + e4];
        #pragma unroll
        for (int st = 1; st < KS; st <<= 1)
            #pragma unroll
            for (int i = 0; i < KS; i += 2 * st) {
                t[i].x += t[i + st].x; t[i].y += t[i + st].y;
                t[i].z += t[i + st].z; t[i].w += t[i + st].w;
            }
        float fn = FN[m];
        int base = m * 65 + e4 * 4;
        Sl[base + 0] = t[0].x * fn; Sl[base + 1] = t[0].y * fn;
        Sl[base + 2] = t[0].z * fn; Sl[base + 3] = t[0].w * fn;
    }
    __syncthreads();

    if (tid < BM2) {
        const int m = tid;
        float mx = -3.0e38f;
        for (int e = 0; e < NE; e++) mx = fmaxf(mx, Sl[m * 65 + e]);
        float sum = 0.f;
        for (int e = 0; e < NE; e++) {
            float p = __expf(Sl[m * 65 + e] - mx);
            Pl[m * 65 + e] = p;
            sum += p;
        }
        RS[m] = 1.0f / sum;
    }
    __syncthreads();

    #pragma unroll
    for (int qq = 0; qq < 2; qq++) {            // coalesced probs write
        int f = tid + 256 * qq;
        int m = f >> 4;
        int e0 = (f & 15) * 4;
        float rs = RS[m];
        float4 pv;
        pv.x = Pl[m * 65 + e0 + 0] * rs;
        pv.y = Pl[m * 65 + e0 + 1] * rs;
        pv.z = Pl[m * 65 + e0 + 2] * rs;
        pv.w = Pl[m * 65 + e0 + 3] * rs;
        *(float4*)&probs[(size_t)(tok0 + m) * NE + e0] = pv;
    }

    if (tid < BM2) {                            // destructive top-4, lowest-index ties
        const int m = tid;
        float wv[TOPK]; int idx[TOPK];
        float wsum = 0.f;
        #pragma unroll
        for (int kk = 0; kk < TOPK; ++kk) {
            float best = -3.0e38f; int bi = 0;
            for (int e = 0; e < NE; e++) {
                float v = Sl[m * 65 + e];
                if (v > best) { best = v; bi = e; }
            }
            Sl[m * 65 + bi] = -3.4e38f;
            float p = Pl[m * 65 + bi];
            wv[kk] = p; idx[kk] = bi; wsum += p;
        }
        float inv = 1.0f / wsum;
        size_t ob = (size_t)(tok0 + m) * TOPK;
        #pragma unroll
        for (int kk = 0; kk < TOPK; kk++) {
            tkw[ob + kk] = wv[kk] * inv * pes[idx[kk]];
            tki[ob + kk] = (float)idx[kk];      // harness reads flat buffer as float32
        }
    }
}

extern "C" void kernel_launch(void* const* d_in, const int* in_sizes, int n_in,
                              void* d_out, int out_size, void* d_ws, size_t ws_size,
                              hipStream_t stream) {
    const float* x     = (const float*)d_in[0];
    const float* w     = (const float*)d_in[1];
    const float* scale = (const float*)d_in[2];
    const float* pes   = (const float*)d_in[3];
    const int tokens = in_sizes[0] / HDIM;      // 16384

    float* probs = (float*)d_out;
    float* tkw   = probs + (size_t)tokens * NE;
    float* tki   = tkw + (size_t)tokens * TOPK;

    const size_t wtN = (size_t)HDIM * NE;
    const size_t spN = (size_t)tokens * NE;
    const size_t need8 = (wtN + 7 * spN + (size_t)8 * tokens) * sizeof(float);
    const int KS = (ws_size >= need8) ? 8 : 4;

    float* wt   = (float*)d_ws;
    float* spws = wt + wtN;
    float* sq   = spws + (size_t)(KS - 1) * spN;
    float* sp0  = probs;                        // overwritten by finisher

    transpose_w_kernel<<<HDIM / 64, 256, 0, stream>>>(w, scale, wt);

    const int grid1 = (tokens / 256) * KS;      // 512 @ KS=8 -> 2 blocks/CU
    if (KS == 8)
        gemm6_kernel<8><<<grid1, 256, 0, stream>>>(x, wt, sp0, spws, sq, tokens);
    else
        gemm6_kernel<4><<<grid1, 256, 0, stream>>>(x, wt, sp0, spws, sq, tokens);

    const int grid2 = tokens / BM2;             // 512
    if (KS == 8)
        finish6_kernel<8><<<grid2, 256, 0, stream>>>(sp0, spws, sq, pes, probs, tkw, tki, tokens);
    else
        finish6_kernel<4><<<grid2, 256, 0, stream>>>(sp0, spws, sq, pes, probs, tkw, tki, tokens);
}

// Round 7
// 102.970 us; speedup vs baseline: 3.4584x; 1.1702x over previous
//
#include <hip/hip_runtime.h>
#include <cstddef>

#define HDIM 2048
#define NE 64
#define TOPK 4
#define BM2 32

// ---------- transpose+scale pre-pass: wt[k][e] = w[e][k] * scale[k] ----------
__global__ __launch_bounds__(256) void transpose_w_kernel(
    const float* __restrict__ w, const float* __restrict__ scale,
    float* __restrict__ wt)
{
    __shared__ float Wl[64][65];
    const int tid = threadIdx.x;
    const int k0 = blockIdx.x * 64;          // grid = HDIM/64 = 32
    #pragma unroll
    for (int q = 0; q < 4; q++) {
        int f = tid + 256 * q;
        int e = f >> 4;
        int k4 = (f & 15) * 4;
        float4 v = *(const float4*)(w + (size_t)e * HDIM + k0 + k4);
        Wl[e][k4 + 0] = v.x; Wl[e][k4 + 1] = v.y;
        Wl[e][k4 + 2] = v.z; Wl[e][k4 + 3] = v.w;
    }
    __syncthreads();
    #pragma unroll
    for (int q = 0; q < 4; q++) {
        int f = tid + 256 * q;
        int k = f >> 4;
        int e4 = (f & 15) * 4;
        float s = scale[k0 + k];
        float4 v;
        v.x = Wl[e4 + 0][k] * s; v.y = Wl[e4 + 1][k] * s;
        v.z = Wl[e4 + 2][k] * s; v.w = Wl[e4 + 3][k] * s;
        *(float4*)(wt + (size_t)(k0 + k) * NE + e4) = v;
    }
}

// ---------- GEMM: barrier-free wave-autonomous, per-wave private LDS ----------
// 512 threads = 8 waves; each wave owns 64 tokens x 64 experts x KR k-range.
// Grid = (tokens/512)*KS = 256 -> exactly 1 block/CU, 8 waves/CU guaranteed.
// NO __syncthreads anywhere: waves sync only on their own DS ops (in-order).
template<int KS>
__global__ __launch_bounds__(512) void gemm7_kernel(
    const float* __restrict__ x, const float* __restrict__ wt,
    float* __restrict__ sp0,     // partial scores ks=0 (probs region)
    float* __restrict__ spws,    // partial scores ks=1..KS-1
    float* __restrict__ sq,      // [KS][tokens] partial ssq
    int tokens)
{
    constexpr int KR = HDIM / KS;      // 256 @ KS=8
    constexpr int NCH = KR / 8;        // 8-k chunks
    __shared__ float AB[8][2][64][12]; // [wave][A|B][row][12]  (48 KB)

    const int tid = threadIdx.x;
    const int w = tid >> 6;            // wave id (uniform per wave)
    const int l = tid & 63;
    const int ks = blockIdx.x & (KS - 1);
    const int tile = blockIdx.x / KS;
    const int tokw0 = tile * 512 + w * 64;     // this wave's 64 tokens
    const int k0 = ks * KR;

    float (*As)[12] = AB[w][0];
    float (*Bs)[12] = AB[w][1];

    const int tr = l & 7;              // token-octet index (compute)
    const int ec = l >> 3;             // expert-octet (compute)

    // A staging: lane -> (token atok & atok+32, k-half ah)
    const int atok = l >> 1;
    const int ah = l & 1;
    const int aswz = ah ^ ((l >> 4) & 1);      // XOR k-half with (tok>>3)&1
    const float* xa0 = x + (size_t)(tokw0 + atok) * HDIM + k0 + 4 * ah;
    const float* xa1 = xa0 + (size_t)32 * HDIM;

    // B staging: lane -> (k-row bk, expert-octet bm); contiguous 2KB per chunk
    const int bk = l >> 3;
    const int bm = l & 7;
    const float* wb = wt + (size_t)(k0 + bk) * NE + 8 * bm;

    float acc[8][8];
    #pragma unroll
    for (int i = 0; i < 8; i++)
        #pragma unroll
        for (int j = 0; j < 8; j++) acc[i][j] = 0.f;
    float ssq0 = 0.f, ssq1 = 0.f;

    float4 pa0, pa1, pb0, pb1;
    auto LOAD = [&](int c) {
        pa0 = *(const float4*)(xa0 + c * 8);
        pa1 = *(const float4*)(xa1 + c * 8);
        pb0 = *(const float4*)(wb + (size_t)c * 8 * NE);
        pb1 = *(const float4*)(wb + (size_t)c * 8 * NE + 4);
    };
    auto STORE = [&]() {
        *(float4*)&As[atok][4 * aswz] = pa0;
        *(float4*)&As[32 + atok][4 * aswz] = pa1;
        ssq0 += pa0.x*pa0.x + pa0.y*pa0.y + pa0.z*pa0.z + pa0.w*pa0.w;
        ssq1 += pa1.x*pa1.x + pa1.y*pa1.y + pa1.z*pa1.z + pa1.w*pa1.w;
        float pbf[8] = {pb0.x, pb0.y, pb0.z, pb0.w, pb1.x, pb1.y, pb1.z, pb1.w};
        #pragma unroll
        for (int s = 0; s < 8; ++s)
            Bs[8 * s + bm][bk] = pbf[s];       // row = 8*(e&7)+(e>>3), e=8bm+s
    };

    LOAD(0);
    STORE();                                   // vmcnt wait inserted by compiler

    for (int c = 0; c < NCH; ++c) {
        if (c + 1 < NCH) LOAD(c + 1);          // HBM latency hides under compute
        #pragma unroll
        for (int kq = 0; kq < 2; ++kq) {
            float4 Ai[8];
            #pragma unroll
            for (int i = 0; i < 8; ++i)        // rows 8i..8i+7: banks tile, no conflict
                Ai[i] = *(const float4*)&As[8 * i + tr][4 * (kq ^ (i & 1))];
            #pragma unroll
            for (int j = 0; j < 8; ++j) {
                float4 Bf = *(const float4*)&Bs[8 * j + ec][4 * kq];
                #pragma unroll
                for (int i = 0; i < 8; ++i) {
                    acc[i][j] = fmaf(Ai[i].x, Bf.x, acc[i][j]);
                    acc[i][j] = fmaf(Ai[i].y, Bf.y, acc[i][j]);
                    acc[i][j] = fmaf(Ai[i].z, Bf.z, acc[i][j]);
                    acc[i][j] = fmaf(Ai[i].w, Bf.w, acc[i][j]);
                }
            }
        }
        if (c + 1 < NCH) {
            // all chunk-c ds_reads must have landed before overwrite (same wave)
            asm volatile("s_waitcnt lgkmcnt(0)" ::: "memory");
            STORE();
        }
    }

    // ssq: combine the two k-half lanes of each token (lanes 2t, 2t+1)
    ssq0 += __shfl_xor(ssq0, 1, 64);
    ssq1 += __shfl_xor(ssq1, 1, 64);
    if (ah == 0) {
        sq[(size_t)ks * tokens + tokw0 + atok] = ssq0;
        sq[(size_t)ks * tokens + tokw0 + 32 + atok] = ssq1;
    }

    float* sp = (ks == 0) ? sp0 : (spws + (size_t)(ks - 1) * tokens * NE);
    #pragma unroll
    for (int i = 0; i < 8; ++i) {              // token 8i+tr, experts 8ec..8ec+7
        size_t off = (size_t)(tokw0 + 8 * i + tr) * NE + 8 * ec;
        float4 v0 = {acc[i][0], acc[i][1], acc[i][2], acc[i][3]};
        float4 v1 = {acc[i][4], acc[i][5], acc[i][6], acc[i][7]};
        *(float4*)(sp + off) = v0;
        *(float4*)(sp + off + 4) = v1;
    }
}

// ---------- finisher: tree-sum KS partials, rmsnorm, softmax, top-4 ----------
template<int KS>
__global__ __launch_bounds__(256) void finish7_kernel(
    const float* __restrict__ sp0, const float* __restrict__ spws,
    const float* __restrict__ sq, const float* __restrict__ pes,
    float* __restrict__ probs, float* __restrict__ tkw, float* __restrict__ tki,
    int tokens)
{
    __shared__ float Sl[BM2 * 65];
    __shared__ float Pl[BM2 * 65];
    __shared__ float FN[BM2];
    __shared__ float RS[BM2];

    const int tid = threadIdx.x;
    const int tok0 = blockIdx.x * BM2;          // grid = tokens/32

    if (tid < BM2) {
        float q[KS];
        #pragma unroll
        for (int i = 0; i < KS; i++) q[i] = sq[(size_t)i * tokens + tok0 + tid];
        #pragma unroll
        for (int st = 1; st < KS; st <<= 1)
            #pragma unroll
            for (int i = 0; i < KS; i += 2 * st) q[i] += q[i + st];
        FN[tid] = rsqrtf(q[0] * (1.0f / HDIM) + 1e-6f) * 0.022097086912079612f;
    }
    __syncthreads();

    #pragma unroll
    for (int qq = 0; qq < 2; qq++) {
        int f = tid + 256 * qq;                 // 0..511 float4 of 32x64 tile
        int m = f >> 4;
        int e4 = f & 15;
        float4 t[KS];
        t[0] = ((const float4*)sp0)[(size_t)(tok0 + m) * (NE / 4) + e4];
        #pragma unroll
        for (int i = 1; i < KS; i++)
            t[i] = ((const float4*)(spws + (size_t)(i - 1) * tokens * NE))
                       [(size_t)(tok0 + m) * (NE / 4) + e4];
        #pragma unroll
        for (int st = 1; st < KS; st <<= 1)
            #pragma unroll
            for (int i = 0; i < KS; i += 2 * st) {
                t[i].x += t[i + st].x; t[i].y += t[i + st].y;
                t[i].z += t[i + st].z; t[i].w += t[i + st].w;
            }
        float fn = FN[m];
        int base = m * 65 + e4 * 4;
        Sl[base + 0] = t[0].x * fn; Sl[base + 1] = t[0].y * fn;
        Sl[base + 2] = t[0].z * fn; Sl[base + 3] = t[0].w * fn;
    }
    __syncthreads();

    if (tid < BM2) {
        const int m = tid;
        float mx = -3.0e38f;
        for (int e = 0; e < NE; e++) mx = fmaxf(mx, Sl[m * 65 + e]);
        float sum = 0.f;
        for (int e = 0; e < NE; e++) {
            float p = __expf(Sl[m * 65 + e] - mx);
            Pl[m * 65 + e] = p;
            sum += p;
        }
        RS[m] = 1.0f / sum;
    }
    __syncthreads();

    #pragma unroll
    for (int qq = 0; qq < 2; qq++) {            // coalesced probs write
        int f = tid + 256 * qq;
        int m = f >> 4;
        int e0 = (f & 15) * 4;
        float rs = RS[m];
        float4 pv;
        pv.x = Pl[m * 65 + e0 + 0] * rs;
        pv.y = Pl[m * 65 + e0 + 1] * rs;
        pv.z = Pl[m * 65 + e0 + 2] * rs;
        pv.w = Pl[m * 65 + e0 + 3] * rs;
        *(float4*)&probs[(size_t)(tok0 + m) * NE + e0] = pv;
    }

    if (tid < BM2) {                            // destructive top-4, lowest-index ties
        const int m = tid;
        float wv[TOPK]; int idx[TOPK];
        float wsum = 0.f;
        #pragma unroll
        for (int kk = 0; kk < TOPK; ++kk) {
            float best = -3.0e38f; int bi = 0;
            for (int e = 0; e < NE; e++) {
                float v = Sl[m * 65 + e];
                if (v > best) { best = v; bi = e; }
            }
            Sl[m * 65 + bi] = -3.4e38f;
            float p = Pl[m * 65 + bi];
            wv[kk] = p; idx[kk] = bi; wsum += p;
        }
        float inv = 1.0f / wsum;
        size_t ob = (size_t)(tok0 + m) * TOPK;
        #pragma unroll
        for (int kk = 0; kk < TOPK; kk++) {
            tkw[ob + kk] = wv[kk] * inv * pes[idx[kk]];
            tki[ob + kk] = (float)idx[kk];      // harness reads flat buffer as float32
        }
    }
}

extern "C" void kernel_launch(void* const* d_in, const int* in_sizes, int n_in,
                              void* d_out, int out_size, void* d_ws, size_t ws_size,
                              hipStream_t stream) {
    const float* x     = (const float*)d_in[0];
    const float* w     = (const float*)d_in[1];
    const float* scale = (const float*)d_in[2];
    const float* pes   = (const float*)d_in[3];
    const int tokens = in_sizes[0] / HDIM;      // 16384

    float* probs = (float*)d_out;
    float* tkw   = probs + (size_t)tokens * NE;
    float* tki   = tkw + (size_t)tokens * TOPK;

    const size_t wtN = (size_t)HDIM * NE;
    const size_t spN = (size_t)tokens * NE;
    const size_t need8 = (wtN + 7 * spN + (size_t)8 * tokens) * sizeof(float);
    const int KS = (ws_size >= need8) ? 8 : 4;

    float* wt   = (float*)d_ws;
    float* spws = wt + wtN;
    float* sq   = spws + (size_t)(KS - 1) * spN;
    float* sp0  = probs;                        // overwritten by finisher

    transpose_w_kernel<<<HDIM / 64, 256, 0, stream>>>(w, scale, wt);

    const int grid1 = (tokens / 512) * KS;      // 256 @ KS=8 -> 1 block/CU
    if (KS == 8)
        gemm7_kernel<8><<<grid1, 512, 0, stream>>>(x, wt, sp0, spws, sq, tokens);
    else
        gemm7_kernel<4><<<grid1, 512, 0, stream>>>(x, wt, sp0, spws, sq, tokens);

    const int grid2 = tokens / BM2;             // 512
    if (KS == 8)
        finish7_kernel<8><<<grid2, 256, 0, stream>>>(sp0, spws, sq, pes, probs, tkw, tki, tokens);
    else
        finish7_kernel<4><<<grid2, 256, 0, stream>>>(sp0, spws, sq, pes, probs, tkw, tki, tokens);
}

// Round 8
// 102.882 us; speedup vs baseline: 3.4613x; 1.0008x over previous
//
#include <hip/hip_runtime.h>
#include <cstddef>

#define HDIM 2048
#define NE 64
#define TOPK 4
#define BM2 32

// ---------- transpose+scale pre-pass: wt[k][e] = w[e][k] * scale[k] ----------
__global__ __launch_bounds__(256) void transpose_w_kernel(
    const float* __restrict__ w, const float* __restrict__ scale,
    float* __restrict__ wt)
{
    __shared__ float Wl[64][65];
    const int tid = threadIdx.x;
    const int k0 = blockIdx.x * 64;          // grid = HDIM/64 = 32
    #pragma unroll
    for (int q = 0; q < 4; q++) {
        int f = tid + 256 * q;
        int e = f >> 4;
        int k4 = (f & 15) * 4;
        float4 v = *(const float4*)(w + (size_t)e * HDIM + k0 + k4);
        Wl[e][k4 + 0] = v.x; Wl[e][k4 + 1] = v.y;
        Wl[e][k4 + 2] = v.z; Wl[e][k4 + 3] = v.w;
    }
    __syncthreads();
    #pragma unroll
    for (int q = 0; q < 4; q++) {
        int f = tid + 256 * q;
        int k = f >> 4;
        int e4 = (f & 15) * 4;
        float s = scale[k0 + k];
        float4 v;
        v.x = Wl[e4 + 0][k] * s; v.y = Wl[e4 + 1][k] * s;
        v.z = Wl[e4 + 2][k] * s; v.w = Wl[e4 + 3][k] * s;
        *(float4*)(wt + (size_t)(k0 + k) * NE + e4) = v;
    }
}

// ---------- GEMM: barrier-free wave-autonomous, per-wave private LDS ----------
// 512 threads = 8 waves; each wave owns 64 tokens x 64 experts x KR k-range.
// Grid = 256 -> 1 block/CU, 8 waves/CU (2/SIMD). __launch_bounds__(512,2)
// matches that: VGPR cap 256 (round-7's default heuristic capped at 124 and
// starved the inner loop of ILP registers).
template<int KS>
__global__ __launch_bounds__(512, 2) void gemm8_kernel(
    const float* __restrict__ x, const float* __restrict__ wt,
    float* __restrict__ sp0,     // partial scores ks=0 (probs region)
    float* __restrict__ spws,    // partial scores ks=1..KS-1
    float* __restrict__ sq,      // [KS][tokens] partial ssq
    int tokens)
{
    constexpr int KR = HDIM / KS;      // 256 @ KS=8
    constexpr int NCH = KR / 8;        // 8-k chunks
    __shared__ float AB[8][2][64][12]; // [wave][A|B][row][12]  (48 KB)

    const int tid = threadIdx.x;
    const int w = tid >> 6;            // wave id (uniform per wave)
    const int l = tid & 63;
    const int ks = blockIdx.x & (KS - 1);
    const int tile = blockIdx.x / KS;
    const int tokw0 = tile * 512 + w * 64;     // this wave's 64 tokens
    const int k0 = ks * KR;

    float (*As)[12] = AB[w][0];
    float (*Bs)[12] = AB[w][1];

    const int tr = l & 7;              // token-octet index (compute)
    const int ec = l >> 3;             // expert-octet (compute)

    // A staging: lane -> (token atok & atok+32, k-half ah)
    const int atok = l >> 1;
    const int ah = l & 1;
    const int aswz = ah ^ ((l >> 4) & 1);      // XOR k-half with (tok>>3)&1
    const float* xa0 = x + (size_t)(tokw0 + atok) * HDIM + k0 + 4 * ah;
    const float* xa1 = xa0 + (size_t)32 * HDIM;

    // B staging: lane -> (k-row bk, expert-octet bm); contiguous 2KB per chunk
    const int bk = l >> 3;
    const int bm = l & 7;
    const float* wb = wt + (size_t)(k0 + bk) * NE + 8 * bm;

    float acc[8][8];
    #pragma unroll
    for (int i = 0; i < 8; i++)
        #pragma unroll
        for (int j = 0; j < 8; j++) acc[i][j] = 0.f;
    float ssq0 = 0.f, ssq1 = 0.f;

    float4 pa0, pa1, pb0, pb1;
    auto LOAD = [&](int c) {
        pa0 = *(const float4*)(xa0 + c * 8);
        pa1 = *(const float4*)(xa1 + c * 8);
        pb0 = *(const float4*)(wb + (size_t)c * 8 * NE);
        pb1 = *(const float4*)(wb + (size_t)c * 8 * NE + 4);
    };
    auto STORE = [&]() {
        *(float4*)&As[atok][4 * aswz] = pa0;
        *(float4*)&As[32 + atok][4 * aswz] = pa1;
        ssq0 += pa0.x*pa0.x + pa0.y*pa0.y + pa0.z*pa0.z + pa0.w*pa0.w;
        ssq1 += pa1.x*pa1.x + pa1.y*pa1.y + pa1.z*pa1.z + pa1.w*pa1.w;
        float pbf[8] = {pb0.x, pb0.y, pb0.z, pb0.w, pb1.x, pb1.y, pb1.z, pb1.w};
        #pragma unroll
        for (int s = 0; s < 8; ++s)
            Bs[8 * s + bm][bk] = pbf[s];       // row = 8*(e&7)+(e>>3), e=8bm+s
    };

    LOAD(0);
    STORE();                                   // vmcnt wait inserted by compiler

    for (int c = 0; c < NCH; ++c) {
        if (c + 1 < NCH) LOAD(c + 1);          // HBM latency hides under compute

        // hoist ALL B-fragment reads of the chunk: 16 back-to-back ds_reads
        // (pipelined), 64 VGPR. FMA blocks below then run register-only.
        float4 Bf[2][8];
        #pragma unroll
        for (int kq = 0; kq < 2; ++kq)
            #pragma unroll
            for (int j = 0; j < 8; ++j)
                Bf[kq][j] = *(const float4*)&Bs[8 * j + ec][4 * kq];

        #pragma unroll
        for (int kq = 0; kq < 2; ++kq) {
            float4 Ai[8];
            #pragma unroll
            for (int i = 0; i < 8; ++i)        // rows 8i..8i+7: banks tile, no conflict
                Ai[i] = *(const float4*)&As[8 * i + tr][4 * (kq ^ (i & 1))];
            #pragma unroll
            for (int j = 0; j < 8; ++j) {
                #pragma unroll
                for (int i = 0; i < 8; ++i) {
                    acc[i][j] = fmaf(Ai[i].x, Bf[kq][j].x, acc[i][j]);
                    acc[i][j] = fmaf(Ai[i].y, Bf[kq][j].y, acc[i][j]);
                    acc[i][j] = fmaf(Ai[i].z, Bf[kq][j].z, acc[i][j]);
                    acc[i][j] = fmaf(Ai[i].w, Bf[kq][j].w, acc[i][j]);
                }
            }
        }
        if (c + 1 < NCH) {
            // all chunk-c ds_reads must have landed before pane overwrite (same wave)
            asm volatile("s_waitcnt lgkmcnt(0)" ::: "memory");
            STORE();
        }
    }

    // ssq: combine the two k-half lanes of each token (lanes 2t, 2t+1)
    ssq0 += __shfl_xor(ssq0, 1, 64);
    ssq1 += __shfl_xor(ssq1, 1, 64);
    if (ah == 0) {
        sq[(size_t)ks * tokens + tokw0 + atok] = ssq0;
        sq[(size_t)ks * tokens + tokw0 + 32 + atok] = ssq1;
    }

    float* sp = (ks == 0) ? sp0 : (spws + (size_t)(ks - 1) * tokens * NE);
    #pragma unroll
    for (int i = 0; i < 8; ++i) {              // token 8i+tr, experts 8ec..8ec+7
        size_t off = (size_t)(tokw0 + 8 * i + tr) * NE + 8 * ec;
        float4 v0 = {acc[i][0], acc[i][1], acc[i][2], acc[i][3]};
        float4 v1 = {acc[i][4], acc[i][5], acc[i][6], acc[i][7]};
        *(float4*)(sp + off) = v0;
        *(float4*)(sp + off + 4) = v1;
    }
}

// ---------- finisher: tree-sum KS partials, rmsnorm, softmax, top-4 ----------
template<int KS>
__global__ __launch_bounds__(256) void finish8_kernel(
    const float* __restrict__ sp0, const float* __restrict__ spws,
    const float* __restrict__ sq, const float* __restrict__ pes,
    float* __restrict__ probs, float* __restrict__ tkw, float* __restrict__ tki,
    int tokens)
{
    __shared__ float Sl[BM2 * 65];
    __shared__ float Pl[BM2 * 65];
    __shared__ float FN[BM2];
    __shared__ float RS[BM2];

    const int tid = threadIdx.x;
    const int tok0 = blockIdx.x * BM2;          // grid = tokens/32

    if (tid < BM2) {
        float q[KS];
        #pragma unroll
        for (int i = 0; i < KS; i++) q[i] = sq[(size_t)i * tokens + tok0 + tid];
        #pragma unroll
        for (int st = 1; st < KS; st <<= 1)
            #pragma unroll
            for (int i = 0; i < KS; i += 2 * st) q[i] += q[i + st];
        FN[tid] = rsqrtf(q[0] * (1.0f / HDIM) + 1e-6f) * 0.022097086912079612f;
    }
    __syncthreads();

    #pragma unroll
    for (int qq = 0; qq < 2; qq++) {
        int f = tid + 256 * qq;                 // 0..511 float4 of 32x64 tile
        int m = f >> 4;
        int e4 = f & 15;
        float4 t[KS];
        t[0] = ((const float4*)sp0)[(size_t)(tok0 + m) * (NE / 4) + e4];
        #pragma unroll
        for (int i = 1; i < KS; i++)
            t[i] = ((const float4*)(spws + (size_t)(i - 1) * tokens * NE))
                       [(size_t)(tok0 + m) * (NE / 4) + e4];
        #pragma unroll
        for (int st = 1; st < KS; st <<= 1)
            #pragma unroll
            for (int i = 0; i < KS; i += 2 * st) {
                t[i].x += t[i + st].x; t[i].y += t[i + st].y;
                t[i].z += t[i + st].z; t[i].w += t[i + st].w;
            }
        float fn = FN[m];
        int base = m * 65 + e4 * 4;
        Sl[base + 0] = t[0].x * fn; Sl[base + 1] = t[0].y * fn;
        Sl[base + 2] = t[0].z * fn; Sl[base + 3] = t[0].w * fn;
    }
    __syncthreads();

    if (tid < BM2) {
        const int m = tid;
        float mx = -3.0e38f;
        for (int e = 0; e < NE; e++) mx = fmaxf(mx, Sl[m * 65 + e]);
        float sum = 0.f;
        for (int e = 0; e < NE; e++) {
            float p = __expf(Sl[m * 65 + e] - mx);
            Pl[m * 65 + e] = p;
            sum += p;
        }
        RS[m] = 1.0f / sum;
    }
    __syncthreads();

    #pragma unroll
    for (int qq = 0; qq < 2; qq++) {            // coalesced probs write
        int f = tid + 256 * qq;
        int m = f >> 4;
        int e0 = (f & 15) * 4;
        float rs = RS[m];
        float4 pv;
        pv.x = Pl[m * 65 + e0 + 0] * rs;
        pv.y = Pl[m * 65 + e0 + 1] * rs;
        pv.z = Pl[m * 65 + e0 + 2] * rs;
        pv.w = Pl[m * 65 + e0 + 3] * rs;
        *(float4*)&probs[(size_t)(tok0 + m) * NE + e0] = pv;
    }

    if (tid < BM2) {                            // destructive top-4, lowest-index ties
        const int m = tid;
        float wv[TOPK]; int idx[TOPK];
        float wsum = 0.f;
        #pragma unroll
        for (int kk = 0; kk < TOPK; ++kk) {
            float best = -3.0e38f; int bi = 0;
            for (int e = 0; e < NE; e++) {
                float v = Sl[m * 65 + e];
                if (v > best) { best = v; bi = e; }
            }
            Sl[m * 65 + bi] = -3.4e38f;
            float p = Pl[m * 65 + bi];
            wv[kk] = p; idx[kk] = bi; wsum += p;
        }
        float inv = 1.0f / wsum;
        size_t ob = (size_t)(tok0 + m) * TOPK;
        #pragma unroll
        for (int kk = 0; kk < TOPK; kk++) {
            tkw[ob + kk] = wv[kk] * inv * pes[idx[kk]];
            tki[ob + kk] = (float)idx[kk];      // harness reads flat buffer as float32
        }
    }
}

extern "C" void kernel_launch(void* const* d_in, const int* in_sizes, int n_in,
                              void* d_out, int out_size, void* d_ws, size_t ws_size,
                              hipStream_t stream) {
    const float* x     = (const float*)d_in[0];
    const float* w     = (const float*)d_in[1];
    const float* scale = (const float*)d_in[2];
    const float* pes   = (const float*)d_in[3];
    const int tokens = in_sizes[0] / HDIM;      // 16384

    float* probs = (float*)d_out;
    float* tkw   = probs + (size_t)tokens * NE;
    float* tki   = tkw + (size_t)tokens * TOPK;

    const size_t wtN = (size_t)HDIM * NE;
    const size_t spN = (size_t)tokens * NE;
    const size_t need8 = (wtN + 7 * spN + (size_t)8 * tokens) * sizeof(float);
    const int KS = (ws_size >= need8) ? 8 : 4;

    float* wt   = (float*)d_ws;
    float* spws = wt + wtN;
    float* sq   = spws + (size_t)(KS - 1) * spN;
    float* sp0  = probs;                        // overwritten by finisher

    transpose_w_kernel<<<HDIM / 64, 256, 0, stream>>>(w, scale, wt);

    const int grid1 = (tokens / 512) * KS;      // 256 @ KS=8 -> 1 block/CU
    if (KS == 8)
        gemm8_kernel<8><<<grid1, 512, 0, stream>>>(x, wt, sp0, spws, sq, tokens);
    else
        gemm8_kernel<4><<<grid1, 512, 0, stream>>>(x, wt, sp0, spws, sq, tokens);

    const int grid2 = tokens / BM2;             // 512
    if (KS == 8)
        finish8_kernel<8><<<grid2, 256, 0, stream>>>(sp0, spws, sq, pes, probs, tkw, tki, tokens);
    else
        finish8_kernel<4><<<grid2, 256, 0, stream>>>(sp0, spws, sq, pes, probs, tkw, tki, tokens);
}